// Round 7
// baseline (341.932 us; speedup 1.0000x reference)
//
#include <hip/hip_runtime.h>
#include <math.h>

// Exact k-th order statistic + mask, fp32, n = 64*1024*1024.
// Sampled-bracket single-full-pass design. Per-lane private candidate slots
// (no ballots, no wave-serialization), 4x MLP main loop, refine hist keyed on
// low mantissa bits (uniform -> contention-free atomics). Exact verification +
// always-enqueued flag-gated fallback (proven 3-pass radix select).
//
// state: [0]=lo [1]=hi [2]=C_hi [3]=flag [4]=r' [5]=chunkA [6]=rA [7]=binB
//        [8]=junk [9]=fb_thr [10..15]=fb chain [16]=cand_sum [17]=cand_max

#define N_STATE   32
#define SAMP_OFF  32
#define FB1_OFF   (SAMP_OFF + 4096)
#define FB2_OFF   (FB1_OFF + 4096)
#define FB3_OFF   (FB2_OFF + 4096)
#define HREF_OFF  (FB3_OFF + 256)
#define HREF_INTS (4 * 1048576)                 // 4M bins: (u - lo<<20), span<=4
#define FIXED_Z   (HREF_OFF + HREF_INTS)        // zeroed every call (~16.8 MB)
#define PART_OFF  FIXED_Z                       // 4096 chunk partials (no zero)
#define NTHREADS  524288                        // 2048 blocks x 256
#define NWAVES    8192
#define CNTL_OFF  (PART_OFF + 4096)             // per-lane counts (no zero)
#define CAND_OFF  (CNTL_OFF + NTHREADS)
#define SLOTS     32u
#define SEG       2048u                         // SLOTS * 64 lanes

#define FB_WS_INTS (16 + 4096 + 4096 + 256)

typedef float vfloat4 __attribute__((ext_vector_type(4)));

__device__ __forceinline__ unsigned map_bits(unsigned raw) {
    return (raw & 0x80000000u) ? ~raw : (raw | 0x80000000u);
}

// ---------------- workspace zeroing ----------------
__global__ void __launch_bounds__(256)
zero_ws(uint4* __restrict__ p, int n16)
{
    int i = blockIdx.x * 256 + threadIdx.x;
    int s = gridDim.x * 256;
    uint4 z = make_uint4(0u, 0u, 0u, 0u);
    for (; i < n16; i += s) p[i] = z;
}

// ---------------- sample histogram (12-bit), S = 524288 elems ----------------
__global__ void __launch_bounds__(256)
sample_hist(const uint4* __restrict__ x, int n4, unsigned* __restrict__ hist)
{
    __shared__ unsigned lh[4096];
    for (int i = threadIdx.x; i < 4096; i += 256) lh[i] = 0u;
    __syncthreads();
    int t = blockIdx.x * 256 + threadIdx.x;
    int idx = (t >> 2) * 512 + (t & 3);
    if (idx < n4) {
        uint4 v = x[idx];
        atomicAdd(&lh[map_bits(v.x) >> 20], 1u);
        atomicAdd(&lh[map_bits(v.y) >> 20], 1u);
        atomicAdd(&lh[map_bits(v.z) >> 20], 1u);
        atomicAdd(&lh[map_bits(v.w) >> 20], 1u);
    }
    __syncthreads();
    for (int i = threadIdx.x; i < 4096; i += 256) {
        unsigned c = lh[i];
        if (c) atomicAdd(&hist[i], c);
    }
}

// ---------------- bracket from sample CDF (span clamped to 4) ----------------
__global__ void __launch_bounds__(1024)
bracket(const unsigned* __restrict__ samp, unsigned RLO, unsigned RHI,
        unsigned* __restrict__ st)
{
    __shared__ unsigned s[1024];
    __shared__ unsigned sh_lo, sh_hi;
    int t = threadIdx.x;
    if (t == 0) { sh_lo = 0u; sh_hi = 4096u; }
    __syncthreads();
    unsigned v0 = samp[4*t], v1 = samp[4*t+1], v2 = samp[4*t+2], v3 = samp[4*t+3];
    unsigned my = v0 + v1 + v2 + v3;
    s[t] = my;
    __syncthreads();
    for (int off = 1; off < 1024; off <<= 1) {
        unsigned w = (t >= off) ? s[t - off] : 0u;
        __syncthreads();
        s[t] += w;
        __syncthreads();
    }
    unsigned excl = s[t] - my;
    unsigned cb[4] = {excl, excl + v0, excl + v0 + v1, excl + v0 + v1 + v2};
    #pragma unroll
    for (int j = 0; j < 4; ++j) {
        unsigned b = (unsigned)(4*t + j);
        if (cb[j] <= RLO) atomicMax(&sh_lo, b);
        if (cb[j] >= RHI) atomicMin(&sh_hi, b);
    }
    __syncthreads();
    if (t == 0) {
        unsigned L = sh_lo, H = sh_hi;
        if (H > L + 4u) H = L + 4u;      // clamp; exact verification catches misses
        st[0] = L; st[1] = H;
    }
}

// ---------------- the single full pass ----------------
__global__ void __launch_bounds__(256)
pass2(const uint4* __restrict__ x, int n4, vfloat4* __restrict__ out,
      unsigned* __restrict__ href, uint2* __restrict__ cand,
      unsigned* __restrict__ cntl, unsigned* __restrict__ st)
{
    const unsigned lo20 = st[0] << 20;
    const unsigned span = (st[1] << 20) - lo20;
    const unsigned hi20 = lo20 + span;
    const unsigned lane = threadIdx.x & 63u;
    const unsigned tid  = (unsigned)(blockIdx.x * 256 + threadIdx.x);
    const unsigned wave = tid >> 6;
    uint2* segw = cand + (size_t)wave * SEG;   // layout: slot*64 + lane
    unsigned cl = 0, chi = 0;
    const int S = gridDim.x * 256;

    #define PROC(V, IDX) { \
        vfloat4 o; unsigned gi = (unsigned)(IDX) * 4u; \
        unsigned uu[4] = {(V).x, (V).y, (V).z, (V).w}; \
        _Pragma("unroll") \
        for (int j = 0; j < 4; ++j) { \
            unsigned u = map_bits(uu[j]); \
            bool ge = (u >= hi20); chi += ge ? 1u : 0u; \
            o[j] = ge ? 1.0f : 0.0f; \
            unsigned d = u - lo20; \
            if (d < span) { \
                atomicAdd(&href[d], 1u); \
                if (cl < SLOTS) segw[(cl << 6) + lane] = make_uint2(u, gi + (unsigned)j); \
                ++cl; \
            } \
        } \
        __builtin_nontemporal_store(o, &out[IDX]); }

    int i = (int)tid;
    int nmain = n4 - 3 * S;                    // safe bound for 4-wide body
    for (; i < nmain; i += 4 * S) {
        uint4 v0 = x[i];
        uint4 v1 = x[i + S];
        uint4 v2 = x[i + 2 * S];
        uint4 v3 = x[i + 3 * S];
        PROC(v0, i) PROC(v1, i + S) PROC(v2, i + 2 * S) PROC(v3, i + 3 * S)
    }
    for (; i < n4; i += S) { uint4 v = x[i]; PROC(v, i) }
    #undef PROC

    unsigned sum = cl, mx = cl;
    for (int off = 32; off > 0; off >>= 1) {
        sum += __shfl_down(sum, off, 64);
        unsigned om = __shfl_down(mx, off, 64);
        mx = (om > mx) ? om : mx;
        chi += __shfl_down(chi, off, 64);
    }
    if (lane == 0) {
        atomicAdd(&st[2], chi);
        atomicAdd(&st[16], sum);
        atomicMax(&st[17], mx);
    }
    cntl[tid] = (cl > SLOTS) ? SLOTS : cl;
}

// ---------------- exact bracket verification (1 thread) ----------------
__global__ void flagcomp(unsigned n, unsigned r, unsigned* st)
{
    unsigned long long Nc  = st[16];
    unsigned long long Chi = st[2];
    unsigned long long Nlt_hi = (unsigned long long)n - Chi;
    unsigned flag = 0;
    if (st[17] > SLOTS) flag = 1;              // per-lane slot overflow
    if (Nc > Nlt_hi)    flag = 1;
    unsigned long long Nlt_lo = (Nc > Nlt_hi) ? 0ull : (Nlt_hi - Nc);
    if (!((Nlt_lo <= (unsigned long long)r) && ((unsigned long long)r < Nlt_hi)))
        flag = 1;
    st[3] = flag;
    st[4] = (unsigned)((unsigned long long)r - Nlt_lo);
}

// ---------------- refine-hist chunk reduction (gated) ----------------
__global__ void __launch_bounds__(256)
reduce_chunks(const unsigned* __restrict__ href, unsigned* __restrict__ part,
              const unsigned* __restrict__ gate)
{
    if (*gate != 0u) return;
    __shared__ unsigned s[256];
    unsigned sum = 0;
    int base = blockIdx.x * 1024;
    for (int t = threadIdx.x; t < 1024; t += 256) sum += href[base + t];
    s[threadIdx.x] = sum;
    __syncthreads();
    for (int off = 128; off > 0; off >>= 1) {
        if (threadIdx.x < off) s[threadIdx.x] += s[threadIdx.x + off];
        __syncthreads();
    }
    if (threadIdx.x == 0) part[blockIdx.x] = s[0];
}

// ---------------- generic gated single-block select ----------------
__global__ void __launch_bounds__(1024)
scan_select(const unsigned* __restrict__ hist, int nbins,
            const unsigned* __restrict__ chunk_sel, int chunk_mul,
            const unsigned* __restrict__ rank_in, unsigned rank_imm,
            unsigned* __restrict__ bin_out, unsigned* __restrict__ rank_out,
            const unsigned* __restrict__ gate, int want_nonzero)
{
    if (gate) {
        unsigned g = *gate;
        if ((g != 0u) != (want_nonzero != 0)) return;
    }
    __shared__ unsigned s[1024];
    int t = threadIdx.x;
    const unsigned* h = hist + (chunk_sel ? (size_t)(*chunk_sel) * (size_t)chunk_mul : 0);
    unsigned rank = rank_in ? *rank_in : rank_imm;
    int per = (nbins + 1023) >> 10;
    int base = t * per;
    unsigned mySum = 0;
    for (int i = 0; i < per; ++i) {
        int b = base + i;
        if (b < nbins) mySum += h[b];
    }
    s[t] = mySum;
    __syncthreads();
    for (int off = 1; off < 1024; off <<= 1) {
        unsigned v = (t >= off) ? s[t - off] : 0u;
        __syncthreads();
        s[t] += v;
        __syncthreads();
    }
    unsigned incl = s[t];
    unsigned excl = incl - mySum;
    if (rank >= excl && rank < incl) {
        unsigned run = excl;
        for (int i = 0; i < per; ++i) {
            int b = base + i;
            unsigned c = (b < nbins) ? h[b] : 0u;
            if (rank < run + c) { *bin_out = (unsigned)b; *rank_out = rank - run; break; }
            run += c;
        }
    }
}

// ---------------- fixup (gated) ----------------
__global__ void __launch_bounds__(256)
fixup(const uint2* __restrict__ cand, const unsigned* __restrict__ cntl,
      const unsigned* __restrict__ st, float* __restrict__ out)
{
    if (st[3] != 0u) return;
    unsigned thr = (st[0] << 20) + st[5] * 1024u + st[7];
    unsigned tid = (unsigned)(blockIdx.x * 256 + threadIdx.x);
    unsigned lane = tid & 63u;
    const uint2* segw = cand + (size_t)(tid >> 6) * SEG;
    unsigned m = cntl[tid];
    for (unsigned s = 0; s < m; ++s) {
        uint2 cv = segw[(s << 6) + lane];
        if (cv.x >= thr) out[cv.y] = 1.0f;
    }
}

// ---------------- fallback (proven 3-pass radix), flag-gated ----------------
__global__ void __launch_bounds__(256)
hist_pass(const uint4* __restrict__ x, int n4, int shift, int nbins, int mode,
          const unsigned* __restrict__ state, unsigned* __restrict__ hist,
          const unsigned* __restrict__ gate)
{
    if (gate && *gate == 0u) return;
    __shared__ unsigned lh[4096];
    for (int i = threadIdx.x; i < nbins; i += blockDim.x) lh[i] = 0u;
    __syncthreads();

    unsigned tgt = 0; int mshift = 0;
    if (mode == 1)      { tgt = state[0];                      mshift = 20; }
    else if (mode == 2) { tgt = (state[0] << 12) | state[2];   mshift = 8;  }

    const unsigned binmask = (unsigned)(nbins - 1);
    int idx = blockIdx.x * blockDim.x + threadIdx.x;
    int stride = gridDim.x * blockDim.x;
    for (int i = idx; i < n4; i += stride) {
        uint4 v = x[i];
        unsigned u;
        u = map_bits(v.x); if (!mode || (u >> mshift) == tgt) atomicAdd(&lh[(u >> shift) & binmask], 1u);
        u = map_bits(v.y); if (!mode || (u >> mshift) == tgt) atomicAdd(&lh[(u >> shift) & binmask], 1u);
        u = map_bits(v.z); if (!mode || (u >> mshift) == tgt) atomicAdd(&lh[(u >> shift) & binmask], 1u);
        u = map_bits(v.w); if (!mode || (u >> mshift) == tgt) atomicAdd(&lh[(u >> shift) & binmask], 1u);
    }
    __syncthreads();
    for (int i = threadIdx.x; i < nbins; i += blockDim.x) {
        unsigned c = lh[i];
        if (c) atomicAdd(&hist[i], c);
    }
}

__global__ void finalize_thr_fb(unsigned* st, const unsigned* gate) {
    if (gate && *gate == 0u) return;
    unsigned u = (st[10] << 20) | (st[12] << 8) | st[14];
    st[9] = (u & 0x80000000u) ? (u & 0x7FFFFFFFu) : ~u;
}

__global__ void __launch_bounds__(256)
mask_kernel(const float4* __restrict__ x, float4* __restrict__ out, int n4,
            const unsigned* __restrict__ st, const unsigned* __restrict__ gate)
{
    if (gate && *gate == 0u) return;
    float thr = __uint_as_float(st[9]);
    int idx = blockIdx.x * blockDim.x + threadIdx.x;
    int stride = gridDim.x * blockDim.x;
    for (int i = idx; i < n4; i += stride) {
        float4 v = x[i];
        float4 o;
        o.x = (v.x >= thr) ? 1.0f : 0.0f;
        o.y = (v.y >= thr) ? 1.0f : 0.0f;
        o.z = (v.z >= thr) ? 1.0f : 0.0f;
        o.w = (v.w >= thr) ? 1.0f : 0.0f;
        out[i] = o;
    }
}

// ---------------- host ----------------
extern "C" void kernel_launch(void* const* d_in, const int* in_sizes, int n_in,
                              void* d_out, int out_size, void* d_ws, size_t ws_size,
                              hipStream_t stream)
{
    const float* x = (const float*)d_in[0];
    float* out = (float*)d_out;
    long long n = (long long)in_sizes[0];
    long long k = (long long)((double)n * 0.9);   // matches Python int(n * RATIO)

    if (k <= 0) {
        hipMemsetAsync(d_out, 0, (size_t)out_size * sizeof(float), stream);
        return;
    }

    unsigned* ws = (unsigned*)d_ws;
    unsigned* st = ws;
    int n4 = (int)(n / 4);
    const uint4* x4 = (const uint4*)x;
    unsigned r = (unsigned)(n - k);               // ascending rank of threshold

    size_t need_fast = ((size_t)CAND_OFF + (size_t)NWAVES * SEG * 2) * 4;

    if (ws_size >= need_fast) {
        unsigned* samp = ws + SAMP_OFF;
        unsigned* fb1  = ws + FB1_OFF;
        unsigned* fb2  = ws + FB2_OFF;
        unsigned* fb3  = ws + FB3_OFF;
        unsigned* href = ws + HREF_OFF;
        unsigned* part = ws + PART_OFF;
        unsigned* cntl = ws + CNTL_OFF;
        uint2*    cand = (uint2*)(ws + CAND_OFF);

        const unsigned S = 524288u;
        double T = (double)r / (double)n;
        const double EPS = 0.005;
        double tlo = T - EPS; if (tlo < 0.0) tlo = 0.0;
        double thi = T + EPS; if (thi > 1.0) thi = 1.0;
        unsigned RLO = (unsigned)floor(tlo * (double)S);
        unsigned RHI = (unsigned)ceil(thi * (double)S);
        if (RHI > S) RHI = S;

        zero_ws<<<1024, 256, 0, stream>>>((uint4*)d_ws, FIXED_Z / 4);
        sample_hist<<<512, 256, 0, stream>>>(x4, n4, samp);
        bracket<<<1, 1024, 0, stream>>>(samp, RLO, RHI, st);
        pass2<<<2048, 256, 0, stream>>>(x4, n4, (vfloat4*)out, href, cand, cntl, st);
        flagcomp<<<1, 1, 0, stream>>>((unsigned)n, r, st);
        // fast-path select chain (gated on flag==0)
        reduce_chunks<<<4096, 256, 0, stream>>>(href, part, &st[3]);
        scan_select<<<1, 1024, 0, stream>>>(part, 4096, nullptr, 0, &st[4], 0u, &st[5], &st[6], &st[3], 0);
        scan_select<<<1, 1024, 0, stream>>>(href, 1024, &st[5], 1024, &st[6], 0u, &st[7], &st[8], &st[3], 0);
        fixup<<<2048, 256, 0, stream>>>(cand, cntl, st, out);
        // fallback chain (gated on flag!=0) — proven exact path
        hist_pass<<<2048, 256, 0, stream>>>(x4, n4, 20, 4096, 0, &st[10], fb1, &st[3]);
        scan_select<<<1, 1024, 0, stream>>>(fb1, 4096, nullptr, 0, nullptr, r, &st[10], &st[11], &st[3], 1);
        hist_pass<<<2048, 256, 0, stream>>>(x4, n4, 8, 4096, 1, &st[10], fb2, &st[3]);
        scan_select<<<1, 1024, 0, stream>>>(fb2, 4096, nullptr, 0, &st[11], 0u, &st[12], &st[13], &st[3], 1);
        hist_pass<<<2048, 256, 0, stream>>>(x4, n4, 0, 256, 2, &st[10], fb3, &st[3]);
        scan_select<<<1, 1024, 0, stream>>>(fb3, 256, nullptr, 0, &st[13], 0u, &st[14], &st[15], &st[3], 1);
        finalize_thr_fb<<<1, 1, 0, stream>>>(st, &st[3]);
        mask_kernel<<<2048, 256, 0, stream>>>((const float4*)x, (float4*)out, n4, st, &st[3]);
    } else {
        // small-ws standalone fallback: 3-pass radix + mask (ungated)
        unsigned* h1 = ws + 16;
        unsigned* h2 = ws + 16 + 4096;
        unsigned* h3 = ws + 16 + 8192;

        hipMemsetAsync(d_ws, 0, FB_WS_INTS * sizeof(unsigned), stream);

        hist_pass<<<2048, 256, 0, stream>>>(x4, n4, 20, 4096, 0, &ws[10], h1, nullptr);
        scan_select<<<1, 1024, 0, stream>>>(h1, 4096, nullptr, 0, nullptr, r, &ws[10], &ws[11], nullptr, 0);
        hist_pass<<<2048, 256, 0, stream>>>(x4, n4, 8, 4096, 1, &ws[10], h2, nullptr);
        scan_select<<<1, 1024, 0, stream>>>(h2, 4096, nullptr, 0, &ws[11], 0u, &ws[12], &ws[13], nullptr, 0);
        hist_pass<<<2048, 256, 0, stream>>>(x4, n4, 0, 256, 2, &ws[10], h3, nullptr);
        scan_select<<<1, 1024, 0, stream>>>(h3, 256, nullptr, 0, &ws[13], 0u, &ws[14], &ws[15], nullptr, 0);
        finalize_thr_fb<<<1, 1, 0, stream>>>(ws, nullptr);
        mask_kernel<<<2048, 256, 0, stream>>>((const float4*)x, (float4*)out, n4, ws, nullptr);
    }
}